// Round 6
// baseline (393.180 us; speedup 1.0000x reference)
//
#include <hip/hip_runtime.h>

// Bidirectional RNN (H=20, input=1), B=4096, T=2048.
// 16 lanes per chain, 4 chains/wave, 2048 waves -> 2 waves per SIMD (tests
// dual-wave issue: lone wave issues ~1 instr/4cyc; co-resident wave should
// roughly double aggregate issue and fill trans/tail stalls).
// Lane L (0..15 within chain) owns row L fully; shared rows 16..19 are
// k-split across the 4 quads (quad0: k 0-3/8-11, quad1: k 4-7/12-15,
// quad2: k 16-19, quad3: zero) and combined by row_ror:4/8 rotate-reduce.
// All broadcasts are DPP (quad_perm + row_half_mirror + row_ror) -- zero DS
// ops in the inner loop. fp16 dot2 weights/state, r' = S/(1+e^{2a}) affine
// reparametrization (W*1 folded into bias exactly from quantized weights),
// RTZ-bias-corrected packing (S = 1+2^-11). Same numerics as R5.

static constexpr int TT = 2048;
static constexpr int BB = 4096;

using half2v = decltype(__builtin_amdgcn_cvt_pkrtz(0.0f, 0.0f));

// DPP helpers (ctrl must be a literal).
#define DPPI(v, CTRL) __builtin_amdgcn_update_dpp(0, (v), (CTRL), 0xF, 0xF, true)
#define DPPF(v, CTRL) __builtin_bit_cast(float, DPPI(__builtin_bit_cast(int, (v)), (CTRL)))
#define DPPH(v, CTRL) __builtin_bit_cast(half2v, DPPI(__builtin_bit_cast(int, (v)), (CTRL)))
#define QP0H(v) DPPH((v), 0x00)
#define QP1H(v) DPPH((v), 0x55)
#define QP2H(v) DPPH((v), 0xAA)
#define QP3H(v) DPPH((v), 0xFF)
#define QXOR1_F(v) DPPF((v), 0xB1)   // quad_perm [1,0,3,2]
#define HMIRH(v) DPPH((v), 0x141)    // row_half_mirror: l <-> 7-l within 8
#define ROR4_F(v) DPPF((v), 0x124)   // row_ror:4  (within 16-lane row)
#define ROR8_F(v) DPPF((v), 0x128)   // row_ror:8

#define SWZF(v, OFF) __builtin_bit_cast(float, __builtin_amdgcn_ds_swizzle( \
    __builtin_bit_cast(int, (v)), (OFF)))

#if defined(__has_builtin) && __has_builtin(__builtin_amdgcn_fdot2)
#define FDOT2(a, b, c) __builtin_amdgcn_fdot2((a), (b), (c), false)
#else
#define FDOT2(a, b, c) \
  ((c) + (float)(a)[0] * (float)(b)[0] + (float)(a)[1] * (float)(b)[1])
#endif

__device__ __forceinline__ float qf16(float v) {  // RNE f32->fp16->f32
  _Float16 t = (_Float16)v;
  return (float)t;
}
__device__ __forceinline__ half2v mk_h2(float a, float b) {
  half2v t{};
  t[0] = a;  // RNE
  t[1] = b;
  return t;
}

// Constants (same scheme as R5):
//  SC = 2/ln2; S = 1+2^-11 (RTZ pack bias fix); C = 1/S; LGC = log2(1/S);
//  K2S = 2*SC/S (stored Wq = fp16(-K2S*W)); M2S: h = 1 + M2S*r'.
#define SCc  2.8853900817779268f
#define Sc   1.00048828125f
#define CCc  0.9995119571685791f
#define LGCc (-7.0425384e-4f)
#define K2Sc 5.7675648927297470f
#define M2Sc (-1.9990239143371582f)

// One step; E = compile-time element of the float4 x buffer.
#define STEP(E)                                                             \
  do {                                                                      \
    float ro8 = ROR8_F(r_own);                                              \
    half2v pkM = __builtin_amdgcn_cvt_pkrtz(r_own, ro8);                    \
    float dd = QXOR1_F(r_sh);                                               \
    half2v pkT = __builtin_amdgcn_cvt_pkrtz(r_sh, dd);                      \
    half2v t0 = QP0H(pkM), t1 = QP1H(pkM), t2 = QP2H(pkM), t3 = QP3H(pkM);  \
    half2v m0 = HMIRH(t0), m1 = HMIRH(t1), m2 = HMIRH(t2), m3 = HMIRH(t3);  \
    half2v tq0 = QP0H(pkT), tq2 = QP2H(pkT);                                \
    float xv = ((E) == 0 ? xq.x : (E) == 1 ? xq.y : (E) == 2 ? xq.z : xq.w);\
    float aA = __builtin_fmaf(xv, wihO, bcO);                               \
    aA = FDOT2(t0, wT0, aA);                                                \
    aA = FDOT2(t1, wT1, aA);                                                \
    aA = FDOT2(t2, wT2, aA);                                                \
    aA = FDOT2(t3, wT3, aA);                                                \
    aA = FDOT2(tq0, wTl0, aA);                                              \
    float aB = FDOT2(m0, wM0, 0.0f);                                        \
    aB = FDOT2(m1, wM1, aB);                                                \
    aB = FDOT2(m2, wM2, aB);                                                \
    aB = FDOT2(m3, wM3, aB);                                                \
    aB = FDOT2(tq2, wTl1, aB);                                              \
    float aS = __builtin_fmaf(xv, wihS, bcS);                               \
    aS = FDOT2(t0, wS0, aS);                                                \
    aS = FDOT2(t1, wS1, aS);                                                \
    aS = FDOT2(t2, wS2, aS);                                                \
    aS = FDOT2(t3, wS3, aS);                                                \
    aS = FDOT2(tq0, wSt0, aS);                                              \
    aS = FDOT2(tq2, wSt1, aS);                                              \
    float aO = aA + aB;                                                     \
    aS += ROR4_F(aS);                                                       \
    aS += ROR8_F(aS);                                                       \
    float uO = __builtin_amdgcn_exp2f(aO);                                  \
    float uS = __builtin_amdgcn_exp2f(aS);                                  \
    r_own = __builtin_amdgcn_rcpf(uO + CCc);                                \
    r_sh  = __builtin_amdgcn_rcpf(uS + CCc);                                \
  } while (0)

__global__ __launch_bounds__(64, 2) void rnn_bidir_kernel(
    const float* __restrict__ x,
    const float* __restrict__ Wih_f, const float* __restrict__ Whh_f,
    const float* __restrict__ bih_f, const float* __restrict__ bhh_f,
    const float* __restrict__ Wih_b, const float* __restrict__ Whh_b,
    const float* __restrict__ bih_b, const float* __restrict__ bhh_b,
    const float* __restrict__ Wfc, const float* __restrict__ bfc,
    float* __restrict__ out) {
  const int lane = threadIdx.x;
  const int cg = lane >> 4;          // chain within wave (0..3)
  const int L = lane & 15;           // lane within chain: owns row L
  const int cq = L >> 2;             // quad within the 16-lane group (0..3)
  const int p = L & 3;               // pos within quad; shared row = 16+p
  const int d = (blockIdx.x >= 1024) ? 1 : 0;  // 0=fwd, 1=bwd
  const int blk = blockIdx.x & 1023;
  const int b = blk * 4 + cg;        // sequence index 0..4095

  const float* Wih = d ? Wih_b : Wih_f;
  const float* Whh = d ? Whh_b : Whh_f;
  const float* bih = d ? bih_b : bih_f;
  const float* bhh = d ? bhh_b : bhh_f;

  // ---- own-row weight packs (row L), pair order matching broadcast regs ---
  // t_p content on this lane = pkM[4*cq+p] = (r'_{base+p}, r'_{(base+p)^8}),
  // base = 8*(cq>>1) + 4*(cq&1); m_p content = same with ^4.
  const int base = 8 * (cq >> 1) + 4 * (cq & 1);
  const float* wrow = Whh + L * 20;
  half2v wT0, wT1, wT2, wT3, wM0, wM1, wM2, wM3, wTl0, wTl1;
  {
    half2v wT[4], wM[4];
#pragma unroll
    for (int p2 = 0; p2 < 4; ++p2) {
      int e0 = base + p2, e1 = e0 ^ 8, f0 = e0 ^ 4, f1 = f0 ^ 8;
      wT[p2] = mk_h2(-K2Sc * wrow[e0], -K2Sc * wrow[e1]);
      wM[p2] = mk_h2(-K2Sc * wrow[f0], -K2Sc * wrow[f1]);
    }
    wT0 = wT[0]; wT1 = wT[1]; wT2 = wT[2]; wT3 = wT[3];
    wM0 = wM[0]; wM1 = wM[1]; wM2 = wM[2]; wM3 = wM[3];
    wTl0 = mk_h2(-K2Sc * wrow[16], -K2Sc * wrow[17]);
    wTl1 = mk_h2(-K2Sc * wrow[18], -K2Sc * wrow[19]);
  }
  // Exact W*1 compensation over the stored (dequantized) own-row weights.
  float Kown;
  {
    float s = 0.f;
    s += (float)wT0[0] + (float)wT0[1] + (float)wM0[0] + (float)wM0[1];
    s += (float)wT1[0] + (float)wT1[1] + (float)wM1[0] + (float)wM1[1];
    s += (float)wT2[0] + (float)wT2[1] + (float)wM2[0] + (float)wM2[1];
    s += (float)wT3[0] + (float)wT3[1] + (float)wM3[0] + (float)wM3[1];
    s += (float)wTl0[0] + (float)wTl0[1] + (float)wTl1[0] + (float)wTl1[1];
    Kown = -(Sc * 0.5f) * s;
  }

  // ---- shared-row (16+p) slice packs -------------------------------------
  // quad0: k {0..3}+{8..11} via t0..t3; quad1: k {4..7}+{12..15} via t0..t3;
  // quad2: k {16..19} via tq0,tq2; quad3: zero.
  const float* srow = Whh + (16 + p) * 20;
  half2v wS0, wS1, wS2, wS3, wSt0, wSt1;
  {
    half2v z = mk_h2(0.f, 0.f);
    if (cq < 2) {
      int b2 = 4 * (cq & 1);
      half2v wS[4];
#pragma unroll
      for (int p2 = 0; p2 < 4; ++p2)
        wS[p2] = mk_h2(-K2Sc * srow[b2 + p2], -K2Sc * srow[b2 + p2 + 8]);
      wS0 = wS[0]; wS1 = wS[1]; wS2 = wS[2]; wS3 = wS[3];
      wSt0 = z; wSt1 = z;
    } else if (cq == 2) {
      wS0 = z; wS1 = z; wS2 = z; wS3 = z;
      wSt0 = mk_h2(-K2Sc * srow[16], -K2Sc * srow[17]);
      wSt1 = mk_h2(-K2Sc * srow[18], -K2Sc * srow[19]);
    } else {
      wS0 = z; wS1 = z; wS2 = z; wS3 = z; wSt0 = z; wSt1 = z;
    }
  }
  // Shared-row bias/x/compensation: carried ONCE per row (on quad0's lane).
  float wihS = 0.f, bcS = 0.f;
  if (cq == 0) {
    float s = 0.f;
    for (int k = 0; k < 20; ++k) s += qf16(-K2Sc * srow[k]);
    float Ksh = -(Sc * 0.5f) * s;
    wihS = SCc * Wih[16 + p];
    bcS = SCc * (bih[16 + p] + bhh[16 + p]) + Ksh + LGCc;
  }

  const float wihO = SCc * Wih[L];
  const float bcO = SCc * (bih[L] + bhh[L]) + Kown + LGCc;
  // fc weights: even chain -> W_fc[0:20], odd -> W_fc[20:40].
  const float wfcO = Wfc[(b & 1) * 20 + L];
  const float wfcS = (cq == 0) ? Wfc[(b & 1) * 20 + 16 + p] : 0.f;

  const float* xrow = x + (size_t)b * TT;
  // h = 0  <=>  r' = S/2; fp16(S/2) == 0.5 exactly.
  float r_own = 0.5f, r_sh = 0.5f;

  // All 16 lanes of a chain load the same float4 (4 steps); bwd mirrored.
  auto xload = [&](int s4) -> float4 {
    int bs = d ? (TT - 4 - s4) : s4;
    float4 v = *reinterpret_cast<const float4*>(xrow + bs);
    if (d) {
      float t = v.x; v.x = v.w; v.w = t;
      t = v.y; v.y = v.z; v.z = t;
    }
    return v;
  };

  float4 xq = xload(0);
  for (int s4 = 0; s4 < TT; s4 += 4) {
    float4 xn = xq;
    if (s4 + 4 < TT) xn = xload(s4 + 4);  // prefetch next 4 steps
    STEP(0); STEP(1); STEP(2); STEP(3);
    xq = xn;
  }

  // Epilogue: h_i = 1 + M2S*r'_i. Reduce over 32 lanes (chain pair) for the
  // paired 40-wide fc row; ds_swizzle fine outside the hot loop.
  float hO = __builtin_fmaf(r_own, M2Sc, 1.0f);
  float hS = __builtin_fmaf(r_sh, M2Sc, 1.0f);
  float pp = wfcO * hO;
  pp = __builtin_fmaf(wfcS, hS, pp);
  pp += SWZF(pp, 0x041F);  // xor 1
  pp += SWZF(pp, 0x081F);  // xor 2
  pp += SWZF(pp, 0x101F);  // xor 4
  pp += SWZF(pp, 0x201F);  // xor 8
  pp += SWZF(pp, 0x401F);  // xor 16 -> sum over 32-lane chain pair
  if ((lane & 31) == 0) {
    int oidx = d * (BB / 2) + blk * 2 + (lane >> 5);
    out[oidx] = pp + bfc[0];
  }
}

extern "C" void kernel_launch(void* const* d_in, const int* in_sizes, int n_in,
                              void* d_out, int out_size, void* d_ws,
                              size_t ws_size, hipStream_t stream) {
  (void)in_sizes; (void)n_in; (void)d_ws; (void)ws_size; (void)out_size;
  const float* x     = (const float*)d_in[0];
  const float* Wih_f = (const float*)d_in[1];
  const float* Whh_f = (const float*)d_in[2];
  const float* bih_f = (const float*)d_in[3];
  const float* bhh_f = (const float*)d_in[4];
  const float* Wih_b = (const float*)d_in[5];
  const float* Whh_b = (const float*)d_in[6];
  const float* bih_b = (const float*)d_in[7];
  const float* bhh_b = (const float*)d_in[8];
  const float* Wfc   = (const float*)d_in[9];
  const float* bfc   = (const float*)d_in[10];
  float* out = (float*)d_out;

  // 1024 fwd + 1024 bwd blocks, 1 wave each (4 chains/wave) = 2 waves/SIMD.
  hipLaunchKernelGGL(rnn_bidir_kernel, dim3(2048), dim3(64), 0, stream,
                     x, Wih_f, Whh_f, bih_f, bhh_f,
                     Wih_b, Whh_b, bih_b, bhh_b, Wfc, bfc, out);
}

// Round 7
// 329.493 us; speedup vs baseline: 1.1933x; 1.1933x over previous
//
#include <hip/hip_runtime.h>

// Bidirectional RNN (H=20, input=1), B=4096, T=2048.
// R5 structure (8 lanes/chain, 8 chains/wave, 1024 waves = 1/SIMD), with a
// trans-pipe-aware schedule: the 6 quarter-rate trans ops per step (3 exp2 +
// 3 rcp) are spaced through the dot2 stream with sched_barrier(0) fences so
// their 16-cyc drains hide under VALU issue instead of serializing (R5 lost
// ~96 cyc/step to back-to-back trans). The last rcp (shared row) is carried
// across the step boundary: its pack + rA/rB derivation happens at the NEXT
// step's head, under the 8 independent DPP broadcasts.
// Numerics identical to R5: fp16 dot2 weights/state, r' = S/(1+e^{2a}),
// W*1 folded into bias exactly from quantized weights, RTZ-bias-corrected
// packing (S = 1+2^-11), 2/ln2 folded into weights/bias.

static constexpr int TT = 2048;   // sequence length
static constexpr int BB = 4096;   // batch

using half2v = decltype(__builtin_amdgcn_cvt_pkrtz(0.0f, 0.0f));

// DPP helpers (ctrl must be a literal).
#define DPPI(v, CTRL) __builtin_amdgcn_update_dpp(0, (v), (CTRL), 0xF, 0xF, true)
#define DPPF(v, CTRL) __builtin_bit_cast(float, DPPI(__builtin_bit_cast(int, (v)), (CTRL)))
#define DPPH(v, CTRL) __builtin_bit_cast(half2v, DPPI(__builtin_bit_cast(int, (v)), (CTRL)))
#define QP0H(v) DPPH((v), 0x00)
#define QP1H(v) DPPH((v), 0x55)
#define QP2H(v) DPPH((v), 0xAA)
#define QP3H(v) DPPH((v), 0xFF)
#define QXOR1_F(v) DPPF((v), 0xB1)   // quad_perm [1,0,3,2]
#define HMIRH(v) DPPH((v), 0x141)    // row_half_mirror: l <-> 7-l within 8
#define HMIRF(v) DPPF((v), 0x141)

#define SWZF(v, OFF) __builtin_bit_cast(float, __builtin_amdgcn_ds_swizzle( \
    __builtin_bit_cast(int, (v)), (OFF)))

#define SBAR() __builtin_amdgcn_sched_barrier(0)

#if defined(__has_builtin) && __has_builtin(__builtin_amdgcn_fdot2)
#define FDOT2(a, b, c) __builtin_amdgcn_fdot2((a), (b), (c), false)
#else
#define FDOT2(a, b, c) \
  ((c) + (float)(a)[0] * (float)(b)[0] + (float)(a)[1] * (float)(b)[1])
#endif

__device__ __forceinline__ float qf16(float v) {  // RNE f32->fp16->f32
  _Float16 t = (_Float16)v;
  return (float)t;
}
__device__ __forceinline__ half2v mk_h2(float a, float b) {
  half2v t{};
  t[0] = a;  // RNE
  t[1] = b;
  return t;
}

// Constants (same scheme as R5):
//  SC = 2/ln2; S = 1+2^-11 (RTZ pack bias fix); C = 1/S; LGC = log2(1/S);
//  K2S = 2*SC/S (stored Wq = fp16(-K2S*W)); M2S: h = 1 + M2S*r'.
#define SCc  2.8853900817779268f
#define Sc   1.00048828125f
#define CCc  0.9995119571685791f
#define LGCc (-7.0425384e-4f)
#define K2Sc 5.7675648927297470f
#define M2Sc (-1.9990239143371582f)

// One step; E = compile-time element of the float4 x buffer.
// Trans order: u0 | r0 | u1 | r1 | u2 | r2(carried) -- each followed by a
// fence and then >=2-9 independent VALU ops to cover the 16-cyc trans drain.
#define STEP(E)                                                             \
  do {                                                                      \
    half2v t0 = QP0H(pk01), t1 = QP1H(pk01);                                \
    half2v t2 = QP2H(pk01), t3 = QP3H(pk01);                                \
    half2v m0 = HMIRH(t0), m1 = HMIRH(t1), m2 = HMIRH(t2), m3 = HMIRH(t3);  \
    float dd = QXOR1_F(r2v);            /* r2v = prev step's carried rcp */ \
    half2v pkc = __builtin_amdgcn_cvt_pkrtz(r2v, dd);                       \
    half2v rA = QP0H(pkc), rB = HMIRH(rA);                                  \
    float xv = ((E) == 0 ? xq.x : (E) == 1 ? xq.y : (E) == 2 ? xq.z : xq.w);\
    float a0a = __builtin_fmaf(xv, wihv[0], bcv[0]);                        \
    a0a = FDOT2(t0, wAq[0][0], a0a);                                        \
    a0a = FDOT2(t1, wAq[0][1], a0a);                                        \
    a0a = FDOT2(t2, wAq[0][2], a0a);                                        \
    a0a = FDOT2(t3, wAq[0][3], a0a);                                        \
    float a0b = FDOT2(m0, wBq[0][0], 0.0f);                                 \
    a0b = FDOT2(m1, wBq[0][1], a0b);                                        \
    a0b = FDOT2(m2, wBq[0][2], a0b);                                        \
    a0b = FDOT2(m3, wBq[0][3], a0b);                                        \
    a0a = FDOT2(rA, wA8[0], a0a);                                           \
    a0b = FDOT2(rB, wB9[0], a0b);                                           \
    float a0 = a0a + a0b;                                                   \
    float u0 = __builtin_amdgcn_exp2f(a0);                                  \
    SBAR();                                                                 \
    float a1a = __builtin_fmaf(xv, wihv[1], bcv[1]);                        \
    a1a = FDOT2(t0, wAq[1][0], a1a);                                        \
    a1a = FDOT2(t1, wAq[1][1], a1a);                                        \
    a1a = FDOT2(t2, wAq[1][2], a1a);                                        \
    a1a = FDOT2(t3, wAq[1][3], a1a);                                        \
    float a1b = FDOT2(m0, wBq[1][0], 0.0f);                                 \
    a1b = FDOT2(m1, wBq[1][1], a1b);                                        \
    a1b = FDOT2(m2, wBq[1][2], a1b);                                        \
    a1b = FDOT2(m3, wBq[1][3], a1b);                                        \
    float v0 = u0 + CCc;                                                    \
    float r0n = __builtin_amdgcn_rcpf(v0);                                  \
    SBAR();                                                                 \
    a1a = FDOT2(rA, wA8[1], a1a);                                           \
    a1b = FDOT2(rB, wB9[1], a1b);                                           \
    float a1 = a1a + a1b;                                                   \
    float u1 = __builtin_amdgcn_exp2f(a1);                                  \
    SBAR();                                                                 \
    float a2p = __builtin_fmaf(xv, wihv[2], bcv[2]);                        \
    a2p = FDOT2(t0, w2q[0], a2p);                                           \
    a2p = FDOT2(t1, w2q[1], a2p);                                           \
    a2p = FDOT2(t2, w2q[2], a2p);                                           \
    a2p = FDOT2(t3, w2q[3], a2p);                                           \
    a2p = FDOT2(rA, w2q[4], a2p);                                           \
    float v1 = u1 + CCc;                                                    \
    float r1n = __builtin_amdgcn_rcpf(v1);                                  \
    SBAR();                                                                 \
    float a2m = HMIRF(a2p);                                                 \
    float a2 = a2p + a2m;                                                   \
    float u2 = __builtin_amdgcn_exp2f(a2);                                  \
    SBAR();                                                                 \
    r0v = r0n;                                                              \
    r1v = r1n;                                                              \
    pk01 = __builtin_amdgcn_cvt_pkrtz(r0n, r1n);                            \
    float v2 = u2 + CCc;                                                    \
    r2v = __builtin_amdgcn_rcpf(v2);    /* packed at NEXT step's head */    \
    SBAR();                                                                 \
  } while (0)

__global__ __launch_bounds__(64, 1) void rnn_bidir_kernel(
    const float* __restrict__ x,
    const float* __restrict__ Wih_f, const float* __restrict__ Whh_f,
    const float* __restrict__ bih_f, const float* __restrict__ bhh_f,
    const float* __restrict__ Wih_b, const float* __restrict__ Whh_b,
    const float* __restrict__ bih_b, const float* __restrict__ bhh_b,
    const float* __restrict__ Wfc, const float* __restrict__ bfc,
    float* __restrict__ out) {
  const int lane = threadIdx.x;
  const int g = lane >> 3;            // chain within wave (0..7)
  const int r = lane & 7;             // row-lane
  const int qhi = (lane >> 2) & 1;    // quad within the 8-lane group
  const int d = (blockIdx.x >= 512) ? 1 : 0;  // 0=fwd, 1=bwd
  const int blk = blockIdx.x & 511;
  const int b = blk * 8 + g;          // sequence index

  const float* Wih = d ? Wih_b : Wih_f;
  const float* Whh = d ? Whh_b : Whh_f;
  const float* bih = d ? bih_b : bih_f;
  const float* bhh = d ? bhh_b : bhh_f;

  const int r2row = 16 + ((r < 4) ? r : (7 - r));  // shared row (k-split)
  const int row01[2] = {r, r + 8};

  // Load the 3 fp32 rows.
  float w[3][20];
#pragma unroll
  for (int i = 0; i < 3; ++i) {
    int row = (i < 2) ? row01[i] : r2row;
    const float4* src = reinterpret_cast<const float4*>(Whh + row * 20);
#pragma unroll
    for (int c4 = 0; c4 < 5; ++c4) {
      float4 v = src[c4];
      w[i][c4 * 4 + 0] = v.x;
      w[i][c4 * 4 + 1] = v.y;
      w[i][c4 * 4 + 2] = v.z;
      w[i][c4 * 4 + 3] = v.w;
    }
  }

  // Quantized weight packs (Wq = fp16(-K2S*W)) + exact W*1 compensation
  // K_row = -(S/2) * sum_k Wq[k] (sum of the dequantized stored values).
  half2v wAq[2][4], wBq[2][4], wA8[2], wB9[2], w2q[5];
  float Krow[3];
#pragma unroll
  for (int i = 0; i < 2; ++i) {
    float sq = 0.f;
#pragma unroll
    for (int k = 0; k < 20; ++k) sq += qf16(-K2Sc * w[i][k]);
    Krow[i] = -(Sc * 0.5f) * sq;
#pragma unroll
    for (int s = 0; s < 4; ++s) {
      int sA = qhi ? s + 4 : s;   // t_s delivers slot sA on my quad
      int sB = qhi ? s : s + 4;   // m_s delivers slot sB
      wAq[i][s] = mk_h2(-K2Sc * w[i][sA], -K2Sc * w[i][sA + 8]);
      wBq[i][s] = mk_h2(-K2Sc * w[i][sB], -K2Sc * w[i][sB + 8]);
    }
    wA8[i] = qhi ? mk_h2(-K2Sc * w[i][19], -K2Sc * w[i][18])
                 : mk_h2(-K2Sc * w[i][16], -K2Sc * w[i][17]);
    wB9[i] = qhi ? mk_h2(-K2Sc * w[i][16], -K2Sc * w[i][17])
                 : mk_h2(-K2Sc * w[i][19], -K2Sc * w[i][18]);
  }
  {
    float sq = 0.f;
#pragma unroll
    for (int k = 0; k < 20; ++k) sq += qf16(-K2Sc * w[2][k]);
    Krow[2] = -(Sc * 0.5f) * sq;
#pragma unroll
    for (int s = 0; s < 4; ++s) {
      int k0 = qhi ? 4 + s : s;   // my quad's k-half: q0 {0..3}, q1 {4..7}
      w2q[s] = mk_h2(-K2Sc * w[2][k0], -K2Sc * w[2][k0 + 8]);
    }
    w2q[4] = qhi ? mk_h2(-K2Sc * w[2][19], -K2Sc * w[2][18])
                 : mk_h2(-K2Sc * w[2][16], -K2Sc * w[2][17]);
  }

  // Biases (SC-scaled, + K_row + LGC), input weights, fc weights.
  // Row2: only the r<4 partner carries bias/x (other half starts at 0).
  float wihv[3], bcv[3], wfc[3];
#pragma unroll
  for (int i = 0; i < 2; ++i) {
    int row = row01[i];
    wihv[i] = SCc * Wih[row];
    bcv[i] = SCc * (bih[row] + bhh[row]) + Krow[i] + LGCc;
    wfc[i] = Wfc[(g & 1) * 20 + row];
  }
  if (r < 4) {
    wihv[2] = SCc * Wih[r2row];
    bcv[2] = SCc * (bih[r2row] + bhh[r2row]) + Krow[2] + LGCc;
    wfc[2] = Wfc[(g & 1) * 20 + r2row];
  } else {
    wihv[2] = 0.f;
    bcv[2] = 0.f;
    wfc[2] = 0.f;  // duplicated row: counted by the r<4 partner only
  }

  const float* xrow = x + (size_t)b * TT;
  // h = 0  <=>  r' = S/2; fp16(S/2) == 0.5 exactly.
  half2v pk01 = mk_h2(0.5f, 0.5f);
  float r0v = 0.5f, r1v = 0.5f, r2v = 0.5f;

  auto xload = [&](int s4) -> float4 {
    int bs = d ? (TT - 4 - s4) : s4;
    float4 v = *reinterpret_cast<const float4*>(xrow + bs);
    if (d) {
      float t = v.x; v.x = v.w; v.w = t;
      t = v.y; v.y = v.z; v.z = t;
    }
    return v;
  };

  float4 xq = xload(0);
  for (int s4 = 0; s4 < TT; s4 += 4) {
    float4 xn = xq;
    if (s4 + 4 < TT) xn = xload(s4 + 4);  // prefetch next 4 steps
    STEP(0); STEP(1); STEP(2); STEP(3);
    xq = xn;
  }

  // Epilogue: h_i = 1 + M2S*r'_i (true scale; no global unscale needed).
  float h0 = __builtin_fmaf(r0v, M2Sc, 1.0f);
  float h1 = __builtin_fmaf(r1v, M2Sc, 1.0f);
  float h2 = __builtin_fmaf(r2v, M2Sc, 1.0f);
  float p = wfc[0] * h0;
  p = __builtin_fmaf(wfc[1], h1, p);
  p = __builtin_fmaf(wfc[2], h2, p);
  p += SWZF(p, 0x041F);  // xor 1
  p += SWZF(p, 0x081F);  // xor 2
  p += SWZF(p, 0x101F);  // xor 4
  p += SWZF(p, 0x201F);  // xor 8 -> sum over the 16-lane chain pair
  if ((lane & 15) == 0) {
    int oidx = d * (BB / 2) + blk * 4 + (g >> 1);
    out[oidx] = p + bfc[0];
  }
}

extern "C" void kernel_launch(void* const* d_in, const int* in_sizes, int n_in,
                              void* d_out, int out_size, void* d_ws,
                              size_t ws_size, hipStream_t stream) {
  (void)in_sizes; (void)n_in; (void)d_ws; (void)ws_size; (void)out_size;
  const float* x     = (const float*)d_in[0];
  const float* Wih_f = (const float*)d_in[1];
  const float* Whh_f = (const float*)d_in[2];
  const float* bih_f = (const float*)d_in[3];
  const float* bhh_f = (const float*)d_in[4];
  const float* Wih_b = (const float*)d_in[5];
  const float* Whh_b = (const float*)d_in[6];
  const float* bih_b = (const float*)d_in[7];
  const float* bhh_b = (const float*)d_in[8];
  const float* Wfc   = (const float*)d_in[9];
  const float* bfc   = (const float*)d_in[10];
  float* out = (float*)d_out;

  // 512 fwd + 512 bwd blocks, 1 wave each (8 chains/wave) = 1 wave/SIMD.
  hipLaunchKernelGGL(rnn_bidir_kernel, dim3(1024), dim3(64), 0, stream,
                     x, Wih_f, Whh_f, bih_f, bhh_f,
                     Wih_b, Whh_b, bih_b, bhh_b, Wfc, bfc, out);
}

// Round 8
// 231.709 us; speedup vs baseline: 1.6969x; 1.4220x over previous
//
#include <hip/hip_runtime.h>

// Bidirectional RNN (H=20, input=1), B=4096, T=2048.
// R5 structure: 8 lanes/chain, 8 chains/wave, 1024 waves (1/SIMD).
// Lane r owns rows {r, r+8} full-k + half of shared row 16+min(r,7-r)
// (partner lane 7-r owns the other half; combined via row_half_mirror).
// State r' = S/(1+e^{2a}) (affine reparam of tanh; W*1 folded into bias
// exactly from the quantized weights). fp16 dot2 weights/state with
// RTZ-bias-corrected packing (S = 1+2^-11); 2/ln2 folded into weights/bias.
// All broadcasts DPP; zero DS ops in the inner loop; no sched fences.
// R8 changes vs R5 (numerics identical): fully static prologue packing
// (no runtime-indexed arrays -> no scratch spill), 8-step unroll, separate
// fwd/bwd loops (no per-load mirror swaps).

static constexpr int TT = 2048;   // sequence length
static constexpr int BB = 4096;   // batch

using half2v = decltype(__builtin_amdgcn_cvt_pkrtz(0.0f, 0.0f));

// DPP helpers (ctrl must be a literal).
#define DPPI(v, CTRL) __builtin_amdgcn_update_dpp(0, (v), (CTRL), 0xF, 0xF, true)
#define DPPF(v, CTRL) __builtin_bit_cast(float, DPPI(__builtin_bit_cast(int, (v)), (CTRL)))
#define DPPH(v, CTRL) __builtin_bit_cast(half2v, DPPI(__builtin_bit_cast(int, (v)), (CTRL)))
#define QP0H(v) DPPH((v), 0x00)
#define QP1H(v) DPPH((v), 0x55)
#define QP2H(v) DPPH((v), 0xAA)
#define QP3H(v) DPPH((v), 0xFF)
#define QXOR1_F(v) DPPF((v), 0xB1)   // quad_perm [1,0,3,2]
#define HMIRH(v) DPPH((v), 0x141)    // row_half_mirror: l <-> 7-l within 8
#define HMIRF(v) DPPF((v), 0x141)

#define SWZF(v, OFF) __builtin_bit_cast(float, __builtin_amdgcn_ds_swizzle( \
    __builtin_bit_cast(int, (v)), (OFF)))

#if defined(__has_builtin) && __has_builtin(__builtin_amdgcn_fdot2)
#define FDOT2(a, b, c) __builtin_amdgcn_fdot2((a), (b), (c), false)
#else
#define FDOT2(a, b, c) \
  ((c) + (float)(a)[0] * (float)(b)[0] + (float)(a)[1] * (float)(b)[1])
#endif

__device__ __forceinline__ half2v mk_h2(float a, float b) {
  half2v t{};
  t[0] = a;  // RNE f32->fp16
  t[1] = b;
  return t;
}
__device__ __forceinline__ half2v sel_h2(bool c, half2v a, half2v b) {
  // value select (cndmask) -- keeps everything in registers (no indexing)
  int r = c ? __builtin_bit_cast(int, a) : __builtin_bit_cast(int, b);
  return __builtin_bit_cast(half2v, r);
}

// Constants (same scheme as R5):
//  SC = 2/ln2; S = 1+2^-11 (RTZ pack bias fix); C = 1/S; LGC = log2(1/S);
//  K2S = 2*SC/S (stored Wq = fp16(-K2S*W)); M2S: h = 1 + M2S*r'.
#define SCc  2.8853900817779268f
#define Sc   1.00048828125f
#define CCc  0.9995119571685791f
#define LGCc (-7.0425384e-4f)
#define K2Sc 5.7675648927297470f
#define M2Sc (-1.9990239143371582f)

// One step; XV = the (already selected) scalar x_t value.
// Slots: s (0..7) = packed (r'[s], r'[s+8]); rA/rB = tail pairs:
//  quad0: rA=(16,17), rB=(19,18); quad1: rA=(19,18), rB=(16,17)
//  (order absorbed into per-lane weight packs).
#define STEPX(XV)                                                           \
  do {                                                                      \
    half2v t0 = QP0H(pk01), t1 = QP1H(pk01);                                \
    half2v t2 = QP2H(pk01), t3 = QP3H(pk01);                                \
    half2v m0 = HMIRH(t0), m1 = HMIRH(t1), m2 = HMIRH(t2), m3 = HMIRH(t3);  \
    float dd = QXOR1_F(r2v);                                                \
    half2v pkc = __builtin_amdgcn_cvt_pkrtz(r2v, dd);                       \
    half2v rA = QP0H(pkc), rB = HMIRH(rA);                                  \
    float xv = (XV);                                                        \
    float a0a = __builtin_fmaf(xv, wihv0, bcv0);                            \
    float a1a = __builtin_fmaf(xv, wihv1, bcv1);                            \
    float a2p = __builtin_fmaf(xv, wihv2, bcv2);                            \
    a0a = FDOT2(t0, wAq[0][0], a0a);                                        \
    a1a = FDOT2(t0, wAq[1][0], a1a);                                        \
    a2p = FDOT2(t0, w2q[0], a2p);                                           \
    float a0b = FDOT2(m0, wBq[0][0], 0.0f);                                 \
    float a1b = FDOT2(m0, wBq[1][0], 0.0f);                                 \
    a0a = FDOT2(t1, wAq[0][1], a0a);                                        \
    a1a = FDOT2(t1, wAq[1][1], a1a);                                        \
    a2p = FDOT2(t1, w2q[1], a2p);                                           \
    a0b = FDOT2(m1, wBq[0][1], a0b);                                        \
    a1b = FDOT2(m1, wBq[1][1], a1b);                                        \
    a0a = FDOT2(t2, wAq[0][2], a0a);                                        \
    a1a = FDOT2(t2, wAq[1][2], a1a);                                        \
    a2p = FDOT2(t2, w2q[2], a2p);                                           \
    a0b = FDOT2(m2, wBq[0][2], a0b);                                        \
    a1b = FDOT2(m2, wBq[1][2], a1b);                                        \
    a0a = FDOT2(t3, wAq[0][3], a0a);                                        \
    a1a = FDOT2(t3, wAq[1][3], a1a);                                        \
    a2p = FDOT2(t3, w2q[3], a2p);                                           \
    a0b = FDOT2(m3, wBq[0][3], a0b);                                        \
    a1b = FDOT2(m3, wBq[1][3], a1b);                                        \
    a0a = FDOT2(rA, wA8q0, a0a);                                            \
    a0b = FDOT2(rB, wB9q0, a0b);                                            \
    a1a = FDOT2(rA, wA8q1, a1a);                                            \
    a1b = FDOT2(rB, wB9q1, a1b);                                            \
    a2p = FDOT2(rA, w2q[4], a2p);                                           \
    float a0 = a0a + a0b;                                                   \
    float a1 = a1a + a1b;                                                   \
    float a2m = HMIRF(a2p);                                                 \
    float a2 = a2p + a2m;                                                   \
    float u0 = __builtin_amdgcn_exp2f(a0);                                  \
    float u1 = __builtin_amdgcn_exp2f(a1);                                  \
    float u2 = __builtin_amdgcn_exp2f(a2);                                  \
    r0v = __builtin_amdgcn_rcpf(u0 + CCc);                                  \
    r1v = __builtin_amdgcn_rcpf(u1 + CCc);                                  \
    r2v = __builtin_amdgcn_rcpf(u2 + CCc);                                  \
    pk01 = __builtin_amdgcn_cvt_pkrtz(r0v, r1v);                            \
  } while (0)

#define RUN8(e0, e1, e2, e3, e4, e5, e6, e7)                                \
  STEPX(e0); STEPX(e1); STEPX(e2); STEPX(e3);                               \
  STEPX(e4); STEPX(e5); STEPX(e6); STEPX(e7);

__global__ __launch_bounds__(64, 1) void rnn_bidir_kernel(
    const float* __restrict__ x,
    const float* __restrict__ Wih_f, const float* __restrict__ Whh_f,
    const float* __restrict__ bih_f, const float* __restrict__ bhh_f,
    const float* __restrict__ Wih_b, const float* __restrict__ Whh_b,
    const float* __restrict__ bih_b, const float* __restrict__ bhh_b,
    const float* __restrict__ Wfc, const float* __restrict__ bfc,
    float* __restrict__ out) {
  const int lane = threadIdx.x;
  const int g = lane >> 3;            // chain within wave (0..7)
  const int r = lane & 7;             // row-lane
  const bool qhi = ((lane >> 2) & 1) != 0;  // quad within the 8-lane group
  const int d = (blockIdx.x >= 512) ? 1 : 0;  // 0=fwd, 1=bwd
  const int blk = blockIdx.x & 511;
  const int b = blk * 8 + g;          // sequence index

  const float* Wih = d ? Wih_b : Wih_f;
  const float* Whh = d ? Whh_b : Whh_f;
  const float* bih = d ? bih_b : bih_f;
  const float* bhh = d ? bhh_b : bhh_f;

  const int r2row = 16 + ((r < 4) ? r : (7 - r));  // shared row (k-split)

  // ---- fully static per-row quantize+pack (no arrays, no scratch) --------
  // Row layout: f0=k0..3, f1=k4..7, f2=k8..11, f3=k12..15, f4=k16..19.
  // packLO[s] = (k=s,   k=s+8)  -> delivered by t_s on quad0 / m_s on quad1
  // packHI[s] = (k=s+4, k=s+12) -> delivered by m_s on quad0 / t_s on quad1
  // tail: t01=(16,17), t98=(19,18); rA delivers (16,17) on q0 / (19,18) on q1.
  half2v wAq[2][4], wBq[2][4], w2q[5];
  half2v wA8q0, wA8q1, wB9q0, wB9q1;
  float Kr0, Kr1, Kr2;
#define PACK_ROW(rowptr, WA, WB, WA8, WB9, KOUT)                            \
  do {                                                                      \
    const float4* src = reinterpret_cast<const float4*>(rowptr);            \
    float4 f0 = src[0], f1 = src[1], f2 = src[2], f3 = src[3], f4 = src[4]; \
    half2v lo0 = mk_h2(-K2Sc * f0.x, -K2Sc * f2.x);                         \
    half2v lo1 = mk_h2(-K2Sc * f0.y, -K2Sc * f2.y);                         \
    half2v lo2 = mk_h2(-K2Sc * f0.z, -K2Sc * f2.z);                         \
    half2v lo3 = mk_h2(-K2Sc * f0.w, -K2Sc * f2.w);                         \
    half2v hi0 = mk_h2(-K2Sc * f1.x, -K2Sc * f3.x);                         \
    half2v hi1 = mk_h2(-K2Sc * f1.y, -K2Sc * f3.y);                         \
    half2v hi2 = mk_h2(-K2Sc * f1.z, -K2Sc * f3.z);                         \
    half2v hi3 = mk_h2(-K2Sc * f1.w, -K2Sc * f3.w);                         \
    half2v t01 = mk_h2(-K2Sc * f4.x, -K2Sc * f4.y);                         \
    half2v t98 = mk_h2(-K2Sc * f4.w, -K2Sc * f4.z);                         \
    WA[0] = sel_h2(qhi, hi0, lo0); WB[0] = sel_h2(qhi, lo0, hi0);           \
    WA[1] = sel_h2(qhi, hi1, lo1); WB[1] = sel_h2(qhi, lo1, hi1);           \
    WA[2] = sel_h2(qhi, hi2, lo2); WB[2] = sel_h2(qhi, lo2, hi2);           \
    WA[3] = sel_h2(qhi, hi3, lo3); WB[3] = sel_h2(qhi, lo3, hi3);           \
    WA8 = sel_h2(qhi, t98, t01); WB9 = sel_h2(qhi, t01, t98);               \
    float s = 0.f;                                                          \
    s += (float)lo0[0] + (float)lo0[1] + (float)hi0[0] + (float)hi0[1];     \
    s += (float)lo1[0] + (float)lo1[1] + (float)hi1[0] + (float)hi1[1];     \
    s += (float)lo2[0] + (float)lo2[1] + (float)hi2[0] + (float)hi2[1];     \
    s += (float)lo3[0] + (float)lo3[1] + (float)hi3[0] + (float)hi3[1];     \
    s += (float)t01[0] + (float)t01[1] + (float)t98[0] + (float)t98[1];     \
    KOUT = -(Sc * 0.5f) * s;                                                \
  } while (0)

  PACK_ROW(Whh + r * 20, wAq[0], wBq[0], wA8q0, wB9q0, Kr0);
  PACK_ROW(Whh + (r + 8) * 20, wAq[1], wBq[1], wA8q1, wB9q1, Kr1);
  {
    // shared row: my quad's k-half: q0 -> {0..3}+{8..11}, q1 -> {4..7}+{12..15}
    const float4* src = reinterpret_cast<const float4*>(Whh + r2row * 20);
    float4 f0 = src[0], f1 = src[1], f2 = src[2], f3 = src[3], f4 = src[4];
    half2v lo0 = mk_h2(-K2Sc * f0.x, -K2Sc * f2.x);
    half2v lo1 = mk_h2(-K2Sc * f0.y, -K2Sc * f2.y);
    half2v lo2 = mk_h2(-K2Sc * f0.z, -K2Sc * f2.z);
    half2v lo3 = mk_h2(-K2Sc * f0.w, -K2Sc * f2.w);
    half2v hi0 = mk_h2(-K2Sc * f1.x, -K2Sc * f3.x);
    half2v hi1 = mk_h2(-K2Sc * f1.y, -K2Sc * f3.y);
    half2v hi2 = mk_h2(-K2Sc * f1.z, -K2Sc * f3.z);
    half2v hi3 = mk_h2(-K2Sc * f1.w, -K2Sc * f3.w);
    half2v t01 = mk_h2(-K2Sc * f4.x, -K2Sc * f4.y);
    half2v t98 = mk_h2(-K2Sc * f4.w, -K2Sc * f4.z);
    w2q[0] = sel_h2(qhi, hi0, lo0);
    w2q[1] = sel_h2(qhi, hi1, lo1);
    w2q[2] = sel_h2(qhi, hi2, lo2);
    w2q[3] = sel_h2(qhi, hi3, lo3);
    w2q[4] = sel_h2(qhi, t98, t01);
    float s = 0.f;  // full-row W*1 compensation (covers BOTH halves)
    s += (float)lo0[0] + (float)lo0[1] + (float)hi0[0] + (float)hi0[1];
    s += (float)lo1[0] + (float)lo1[1] + (float)hi1[0] + (float)hi1[1];
    s += (float)lo2[0] + (float)lo2[1] + (float)hi2[0] + (float)hi2[1];
    s += (float)lo3[0] + (float)lo3[1] + (float)hi3[0] + (float)hi3[1];
    s += (float)t01[0] + (float)t01[1] + (float)t98[0] + (float)t98[1];
    Kr2 = -(Sc * 0.5f) * s;
  }

  // Biases (SC-scaled + K_row + LGC), input weights, fc weights.
  // Shared row: only the r<4 partner carries bias/x/fc (other half zero).
  const float wihv0 = SCc * Wih[r];
  const float wihv1 = SCc * Wih[r + 8];
  const float bcv0 = SCc * (bih[r] + bhh[r]) + Kr0 + LGCc;
  const float bcv1 = SCc * (bih[r + 8] + bhh[r + 8]) + Kr1 + LGCc;
  const float wfc0 = Wfc[(g & 1) * 20 + r];
  const float wfc1 = Wfc[(g & 1) * 20 + r + 8];
  float wihv2, bcv2, wfc2;
  if (r < 4) {
    wihv2 = SCc * Wih[r2row];
    bcv2 = SCc * (bih[r2row] + bhh[r2row]) + Kr2 + LGCc;
    wfc2 = Wfc[(g & 1) * 20 + r2row];
  } else {
    wihv2 = 0.f;
    bcv2 = 0.f;
    wfc2 = 0.f;
  }

  const float* xrow = x + (size_t)b * TT;
  // h = 0  <=>  r' = S/2; fp16(S/2) == 0.5 exactly.
  half2v pk01 = mk_h2(0.5f, 0.5f);
  float r0v = 0.5f, r1v = 0.5f, r2v = 0.5f;

  if (d == 0) {
    float4 xa = *reinterpret_cast<const float4*>(xrow);
    float4 xb = *reinterpret_cast<const float4*>(xrow + 4);
    for (int s8 = 0; s8 < TT; s8 += 8) {
      float4 na = xa, nb = xb;
      if (s8 + 8 < TT) {
        na = *reinterpret_cast<const float4*>(xrow + s8 + 8);
        nb = *reinterpret_cast<const float4*>(xrow + s8 + 12);
      }
      RUN8(xa.x, xa.y, xa.z, xa.w, xb.x, xb.y, xb.z, xb.w)
      xa = na;
      xb = nb;
    }
  } else {
    // bwd: step t = s8+E consumes x[TT-1-s8-E]
    float4 xa = *reinterpret_cast<const float4*>(xrow + TT - 4);
    float4 xb = *reinterpret_cast<const float4*>(xrow + TT - 8);
    for (int s8 = 0; s8 < TT; s8 += 8) {
      float4 na = xa, nb = xb;
      if (s8 + 8 < TT) {
        na = *reinterpret_cast<const float4*>(xrow + TT - 12 - s8);
        nb = *reinterpret_cast<const float4*>(xrow + TT - 16 - s8);
      }
      RUN8(xa.w, xa.z, xa.y, xa.x, xb.w, xb.z, xb.y, xb.x)
      xa = na;
      xb = nb;
    }
  }

  // Epilogue: h_i = 1 + M2S*r'_i (true scale; no global unscale needed).
  float h0 = __builtin_fmaf(r0v, M2Sc, 1.0f);
  float h1 = __builtin_fmaf(r1v, M2Sc, 1.0f);
  float h2 = __builtin_fmaf(r2v, M2Sc, 1.0f);
  float p = wfc0 * h0;
  p = __builtin_fmaf(wfc1, h1, p);
  p = __builtin_fmaf(wfc2, h2, p);
  p += SWZF(p, 0x041F);  // xor 1
  p += SWZF(p, 0x081F);  // xor 2
  p += SWZF(p, 0x101F);  // xor 4
  p += SWZF(p, 0x201F);  // xor 8 -> sum over the 16-lane chain pair
  if ((lane & 15) == 0) {
    int oidx = d * (BB / 2) + blk * 4 + (g >> 1);
    out[oidx] = p + bfc[0];
  }
}

extern "C" void kernel_launch(void* const* d_in, const int* in_sizes, int n_in,
                              void* d_out, int out_size, void* d_ws,
                              size_t ws_size, hipStream_t stream) {
  (void)in_sizes; (void)n_in; (void)d_ws; (void)ws_size; (void)out_size;
  const float* x     = (const float*)d_in[0];
  const float* Wih_f = (const float*)d_in[1];
  const float* Whh_f = (const float*)d_in[2];
  const float* bih_f = (const float*)d_in[3];
  const float* bhh_f = (const float*)d_in[4];
  const float* Wih_b = (const float*)d_in[5];
  const float* Whh_b = (const float*)d_in[6];
  const float* bih_b = (const float*)d_in[7];
  const float* bhh_b = (const float*)d_in[8];
  const float* Wfc   = (const float*)d_in[9];
  const float* bfc   = (const float*)d_in[10];
  float* out = (float*)d_out;

  // 512 fwd + 512 bwd blocks, 1 wave each (8 chains/wave) = 1 wave/SIMD.
  hipLaunchKernelGGL(rnn_bidir_kernel, dim3(1024), dim3(64), 0, stream,
                     x, Wih_f, Whh_f, bih_f, bhh_f,
                     Wih_b, Whh_b, bih_b, bhh_b, Wfc, bfc, out);
}

// Round 9
// 215.697 us; speedup vs baseline: 1.8228x; 1.0742x over previous
//
#include <hip/hip_runtime.h>

// Bidirectional RNN (H=20, input=1), B=4096, T=2048.
// R8 structure: 8 lanes/chain, 8 chains/wave, 1024 waves (1/SIMD).
// Lane r owns rows {r, r+8} full-k + half of shared row 16+min(r,7-r)
// (partner owns the other half; combined via row_half_mirror).
// State r' = S/(1+e^{2a}); W*1 folded into bias exactly from quantized
// weights; fp16 dot2 with RTZ-bias-corrected packing; 2/ln2 folded in.
// R9 change (order only, same math): software-pipelined step --
//  phase A: rA/rB tail broadcasts + chain seeds (depend only on r2v/pkc,
//           which completes MID-step) -> next step can issue ~60 cyc of
//           work while the previous pk01 tail (exp2/rcp/cvt) drains;
//  phase B: t/m broadcasts from pk01; a2 chain completes FIRST (its
//           exp2/rcp issue early), then merged 13-deep a0/a1 chains.
// No sched fences (R7 lesson) -- source order only, compiler schedules.

static constexpr int TT = 2048;   // sequence length
static constexpr int BB = 4096;   // batch

using half2v = decltype(__builtin_amdgcn_cvt_pkrtz(0.0f, 0.0f));

// DPP helpers (ctrl must be a literal).
#define DPPI(v, CTRL) __builtin_amdgcn_update_dpp(0, (v), (CTRL), 0xF, 0xF, true)
#define DPPF(v, CTRL) __builtin_bit_cast(float, DPPI(__builtin_bit_cast(int, (v)), (CTRL)))
#define DPPH(v, CTRL) __builtin_bit_cast(half2v, DPPI(__builtin_bit_cast(int, (v)), (CTRL)))
#define QP0H(v) DPPH((v), 0x00)
#define QP1H(v) DPPH((v), 0x55)
#define QP2H(v) DPPH((v), 0xAA)
#define QP3H(v) DPPH((v), 0xFF)
#define QXOR1_F(v) DPPF((v), 0xB1)   // quad_perm [1,0,3,2]
#define HMIRH(v) DPPH((v), 0x141)    // row_half_mirror: l <-> 7-l within 8
#define HMIRF(v) DPPF((v), 0x141)

#define SWZF(v, OFF) __builtin_bit_cast(float, __builtin_amdgcn_ds_swizzle( \
    __builtin_bit_cast(int, (v)), (OFF)))

#if defined(__has_builtin) && __has_builtin(__builtin_amdgcn_fdot2)
#define FDOT2(a, b, c) __builtin_amdgcn_fdot2((a), (b), (c), false)
#else
#define FDOT2(a, b, c) \
  ((c) + (float)(a)[0] * (float)(b)[0] + (float)(a)[1] * (float)(b)[1])
#endif

__device__ __forceinline__ half2v mk_h2(float a, float b) {
  half2v t{};
  t[0] = a;  // RNE f32->fp16
  t[1] = b;
  return t;
}
__device__ __forceinline__ half2v sel_h2(bool c, half2v a, half2v b) {
  // value select (cndmask) -- keeps everything in registers (no indexing)
  int r = c ? __builtin_bit_cast(int, a) : __builtin_bit_cast(int, b);
  return __builtin_bit_cast(half2v, r);
}

// Constants (same scheme as R5/R8):
//  SC = 2/ln2; S = 1+2^-11 (RTZ pack bias fix); C = 1/S; LGC = log2(1/S);
//  K2S = 2*SC/S (stored Wq = fp16(-K2S*W)); M2S: h = 1 + M2S*r'.
#define SCc  2.8853900817779268f
#define Sc   1.00048828125f
#define CCc  0.9995119571685791f
#define LGCc (-7.0425384e-4f)
#define K2Sc 5.7675648927297470f
#define M2Sc (-1.9990239143371582f)

// One step; XV = the (already selected) scalar x_t value.
// Slots: s (0..7) = packed (r'[s], r'[s+8]); rA/rB = tail pairs:
//  quad0: rA=(16,17), rB=(19,18); quad1: rA=(19,18), rB=(16,17)
//  (order absorbed into per-lane weight packs).
#define STEPX(XV)                                                           \
  do {                                                                      \
    /* ---- phase A: depends only on r2v (ready mid-previous-step) ---- */  \
    float dd = QXOR1_F(r2v);                                                \
    half2v pkc = __builtin_amdgcn_cvt_pkrtz(r2v, dd);                       \
    half2v rA = QP0H(pkc), rB = HMIRH(rA);                                  \
    float xv = (XV);                                                        \
    float a0 = __builtin_fmaf(xv, wihv0, bcv0);                             \
    float a1 = __builtin_fmaf(xv, wihv1, bcv1);                             \
    float a2p = __builtin_fmaf(xv, wihv2, bcv2);                            \
    a0 = FDOT2(rA, wA8q0, a0);                                              \
    a0 = FDOT2(rB, wB9q0, a0);                                              \
    a1 = FDOT2(rA, wA8q1, a1);                                              \
    a1 = FDOT2(rB, wB9q1, a1);                                              \
    a2p = FDOT2(rA, w2q4, a2p);                                             \
    /* ---- phase B: pk01 broadcasts (previous step's tail) ---- */         \
    half2v t0 = QP0H(pk01), t1 = QP1H(pk01);                                \
    half2v t2 = QP2H(pk01), t3 = QP3H(pk01);                                \
    half2v m0 = HMIRH(t0), m1 = HMIRH(t1), m2 = HMIRH(t2), m3 = HMIRH(t3);  \
    /* a2 chain completes FIRST -> r2v/pkc ready early for next step */     \
    a2p = FDOT2(t0, w2q0, a2p);                                             \
    a2p = FDOT2(t1, w2q1, a2p);                                             \
    a2p = FDOT2(t2, w2q2, a2p);                                             \
    a2p = FDOT2(t3, w2q3, a2p);                                             \
    float a2m = HMIRF(a2p);                                                 \
    float a2 = a2p + a2m;                                                   \
    float u2 = __builtin_amdgcn_exp2f(a2);                                  \
    float v2 = u2 + CCc;                                                    \
    r2v = __builtin_amdgcn_rcpf(v2);                                        \
    /* merged 13-deep a0/a1 chains (no combine adds) */                     \
    a0 = FDOT2(t0, wAq00, a0);                                              \
    a1 = FDOT2(t0, wAq10, a1);                                              \
    a0 = FDOT2(m0, wBq00, a0);                                              \
    a1 = FDOT2(m0, wBq10, a1);                                              \
    a0 = FDOT2(t1, wAq01, a0);                                              \
    a1 = FDOT2(t1, wAq11, a1);                                              \
    a0 = FDOT2(m1, wBq01, a0);                                              \
    a1 = FDOT2(m1, wBq11, a1);                                              \
    a0 = FDOT2(t2, wAq02, a0);                                              \
    a1 = FDOT2(t2, wAq12, a1);                                              \
    a0 = FDOT2(m2, wBq02, a0);                                              \
    a1 = FDOT2(m2, wBq12, a1);                                              \
    a0 = FDOT2(t3, wAq03, a0);                                              \
    a1 = FDOT2(t3, wAq13, a1);                                              \
    a0 = FDOT2(m3, wBq03, a0);                                              \
    a1 = FDOT2(m3, wBq13, a1);                                              \
    float u0 = __builtin_amdgcn_exp2f(a0);                                  \
    float v0 = u0 + CCc;                                                    \
    r0v = __builtin_amdgcn_rcpf(v0);                                        \
    float u1 = __builtin_amdgcn_exp2f(a1);                                  \
    float v1 = u1 + CCc;                                                    \
    r1v = __builtin_amdgcn_rcpf(v1);                                        \
    pk01 = __builtin_amdgcn_cvt_pkrtz(r0v, r1v);                            \
  } while (0)

#define RUN8(e0, e1, e2, e3, e4, e5, e6, e7)                                \
  STEPX(e0); STEPX(e1); STEPX(e2); STEPX(e3);                               \
  STEPX(e4); STEPX(e5); STEPX(e6); STEPX(e7);

__global__ __launch_bounds__(64, 1) void rnn_bidir_kernel(
    const float* __restrict__ x,
    const float* __restrict__ Wih_f, const float* __restrict__ Whh_f,
    const float* __restrict__ bih_f, const float* __restrict__ bhh_f,
    const float* __restrict__ Wih_b, const float* __restrict__ Whh_b,
    const float* __restrict__ bih_b, const float* __restrict__ bhh_b,
    const float* __restrict__ Wfc, const float* __restrict__ bfc,
    float* __restrict__ out) {
  const int lane = threadIdx.x;
  const int g = lane >> 3;            // chain within wave (0..7)
  const int r = lane & 7;             // row-lane
  const bool qhi = ((lane >> 2) & 1) != 0;  // quad within the 8-lane group
  const int d = (blockIdx.x >= 512) ? 1 : 0;  // 0=fwd, 1=bwd
  const int blk = blockIdx.x & 511;
  const int b = blk * 8 + g;          // sequence index

  const float* Wih = d ? Wih_b : Wih_f;
  const float* Whh = d ? Whh_b : Whh_f;
  const float* bih = d ? bih_b : bih_f;
  const float* bhh = d ? bhh_b : bhh_f;

  const int r2row = 16 + ((r < 4) ? r : (7 - r));  // shared row (k-split)

  // ---- fully static per-row quantize+pack (no arrays, no scratch) --------
  // Row layout: f0=k0..3, f1=k4..7, f2=k8..11, f3=k12..15, f4=k16..19.
  // packLO[s] = (k=s,   k=s+8)  -> delivered by t_s on quad0 / m_s on quad1
  // packHI[s] = (k=s+4, k=s+12) -> delivered by m_s on quad0 / t_s on quad1
  // tail: t01=(16,17), t98=(19,18); rA delivers (16,17) on q0 / (19,18) on q1.
  half2v wAq00, wAq01, wAq02, wAq03, wBq00, wBq01, wBq02, wBq03;
  half2v wAq10, wAq11, wAq12, wAq13, wBq10, wBq11, wBq12, wBq13;
  half2v w2q0, w2q1, w2q2, w2q3, w2q4;
  half2v wA8q0, wA8q1, wB9q0, wB9q1;
  float Kr0, Kr1, Kr2;
#define PACK_ROW(rowptr, WA0, WA1, WA2, WA3, WB0, WB1, WB2, WB3, WA8, WB9,  \
                 KOUT)                                                      \
  do {                                                                      \
    const float4* src = reinterpret_cast<const float4*>(rowptr);            \
    float4 f0 = src[0], f1 = src[1], f2 = src[2], f3 = src[3], f4 = src[4]; \
    half2v lo0 = mk_h2(-K2Sc * f0.x, -K2Sc * f2.x);                         \
    half2v lo1 = mk_h2(-K2Sc * f0.y, -K2Sc * f2.y);                         \
    half2v lo2 = mk_h2(-K2Sc * f0.z, -K2Sc * f2.z);                         \
    half2v lo3 = mk_h2(-K2Sc * f0.w, -K2Sc * f2.w);                         \
    half2v hi0 = mk_h2(-K2Sc * f1.x, -K2Sc * f3.x);                         \
    half2v hi1 = mk_h2(-K2Sc * f1.y, -K2Sc * f3.y);                         \
    half2v hi2 = mk_h2(-K2Sc * f1.z, -K2Sc * f3.z);                         \
    half2v hi3 = mk_h2(-K2Sc * f1.w, -K2Sc * f3.w);                         \
    half2v t01 = mk_h2(-K2Sc * f4.x, -K2Sc * f4.y);                         \
    half2v t98 = mk_h2(-K2Sc * f4.w, -K2Sc * f4.z);                         \
    WA0 = sel_h2(qhi, hi0, lo0); WB0 = sel_h2(qhi, lo0, hi0);               \
    WA1 = sel_h2(qhi, hi1, lo1); WB1 = sel_h2(qhi, lo1, hi1);               \
    WA2 = sel_h2(qhi, hi2, lo2); WB2 = sel_h2(qhi, lo2, hi2);               \
    WA3 = sel_h2(qhi, hi3, lo3); WB3 = sel_h2(qhi, lo3, hi3);               \
    WA8 = sel_h2(qhi, t98, t01); WB9 = sel_h2(qhi, t01, t98);               \
    float s = 0.f;                                                          \
    s += (float)lo0[0] + (float)lo0[1] + (float)hi0[0] + (float)hi0[1];     \
    s += (float)lo1[0] + (float)lo1[1] + (float)hi1[0] + (float)hi1[1];     \
    s += (float)lo2[0] + (float)lo2[1] + (float)hi2[0] + (float)hi2[1];     \
    s += (float)lo3[0] + (float)lo3[1] + (float)hi3[0] + (float)hi3[1];     \
    s += (float)t01[0] + (float)t01[1] + (float)t98[0] + (float)t98[1];     \
    KOUT = -(Sc * 0.5f) * s;                                                \
  } while (0)

  PACK_ROW(Whh + r * 20, wAq00, wAq01, wAq02, wAq03, wBq00, wBq01, wBq02,
           wBq03, wA8q0, wB9q0, Kr0);
  PACK_ROW(Whh + (r + 8) * 20, wAq10, wAq11, wAq12, wAq13, wBq10, wBq11,
           wBq12, wBq13, wA8q1, wB9q1, Kr1);
  {
    // shared row: my quad's k-half: q0 -> {0..3}+{8..11}, q1 -> {4..7}+{12..15}
    const float4* src = reinterpret_cast<const float4*>(Whh + r2row * 20);
    float4 f0 = src[0], f1 = src[1], f2 = src[2], f3 = src[3], f4 = src[4];
    half2v lo0 = mk_h2(-K2Sc * f0.x, -K2Sc * f2.x);
    half2v lo1 = mk_h2(-K2Sc * f0.y, -K2Sc * f2.y);
    half2v lo2 = mk_h2(-K2Sc * f0.z, -K2Sc * f2.z);
    half2v lo3 = mk_h2(-K2Sc * f0.w, -K2Sc * f2.w);
    half2v hi0 = mk_h2(-K2Sc * f1.x, -K2Sc * f3.x);
    half2v hi1 = mk_h2(-K2Sc * f1.y, -K2Sc * f3.y);
    half2v hi2 = mk_h2(-K2Sc * f1.z, -K2Sc * f3.z);
    half2v hi3 = mk_h2(-K2Sc * f1.w, -K2Sc * f3.w);
    half2v t01 = mk_h2(-K2Sc * f4.x, -K2Sc * f4.y);
    half2v t98 = mk_h2(-K2Sc * f4.w, -K2Sc * f4.z);
    w2q0 = sel_h2(qhi, hi0, lo0);
    w2q1 = sel_h2(qhi, hi1, lo1);
    w2q2 = sel_h2(qhi, hi2, lo2);
    w2q3 = sel_h2(qhi, hi3, lo3);
    w2q4 = sel_h2(qhi, t98, t01);
    float s = 0.f;  // full-row W*1 compensation (covers BOTH halves)
    s += (float)lo0[0] + (float)lo0[1] + (float)hi0[0] + (float)hi0[1];
    s += (float)lo1[0] + (float)lo1[1] + (float)hi1[0] + (float)hi1[1];
    s += (float)lo2[0] + (float)lo2[1] + (float)hi2[0] + (float)hi2[1];
    s += (float)lo3[0] + (float)lo3[1] + (float)hi3[0] + (float)hi3[1];
    s += (float)t01[0] + (float)t01[1] + (float)t98[0] + (float)t98[1];
    Kr2 = -(Sc * 0.5f) * s;
  }

  // Biases (SC-scaled + K_row + LGC), input weights, fc weights.
  // Shared row: only the r<4 partner carries bias/x/fc (other half zero).
  const float wihv0 = SCc * Wih[r];
  const float wihv1 = SCc * Wih[r + 8];
  const float bcv0 = SCc * (bih[r] + bhh[r]) + Kr0 + LGCc;
  const float bcv1 = SCc * (bih[r + 8] + bhh[r + 8]) + Kr1 + LGCc;
  const float wfc0 = Wfc[(g & 1) * 20 + r];
  const float wfc1 = Wfc[(g & 1) * 20 + r + 8];
  float wihv2, bcv2, wfc2;
  if (r < 4) {
    wihv2 = SCc * Wih[r2row];
    bcv2 = SCc * (bih[r2row] + bhh[r2row]) + Kr2 + LGCc;
    wfc2 = Wfc[(g & 1) * 20 + r2row];
  } else {
    wihv2 = 0.f;
    bcv2 = 0.f;
    wfc2 = 0.f;
  }

  const float* xrow = x + (size_t)b * TT;
  // h = 0  <=>  r' = S/2; fp16(S/2) == 0.5 exactly.
  half2v pk01 = mk_h2(0.5f, 0.5f);
  float r0v = 0.5f, r1v = 0.5f, r2v = 0.5f;

  if (d == 0) {
    float4 xa = *reinterpret_cast<const float4*>(xrow);
    float4 xb = *reinterpret_cast<const float4*>(xrow + 4);
    for (int s8 = 0; s8 < TT - 8; s8 += 8) {
      float4 na = *reinterpret_cast<const float4*>(xrow + s8 + 8);
      float4 nb = *reinterpret_cast<const float4*>(xrow + s8 + 12);
      RUN8(xa.x, xa.y, xa.z, xa.w, xb.x, xb.y, xb.z, xb.w)
      xa = na;
      xb = nb;
    }
    RUN8(xa.x, xa.y, xa.z, xa.w, xb.x, xb.y, xb.z, xb.w)
  } else {
    // bwd: step t = s8+E consumes x[TT-1-s8-E]
    float4 xa = *reinterpret_cast<const float4*>(xrow + TT - 4);
    float4 xb = *reinterpret_cast<const float4*>(xrow + TT - 8);
    for (int s8 = 0; s8 < TT - 8; s8 += 8) {
      float4 na = *reinterpret_cast<const float4*>(xrow + TT - 12 - s8);
      float4 nb = *reinterpret_cast<const float4*>(xrow + TT - 16 - s8);
      RUN8(xa.w, xa.z, xa.y, xa.x, xb.w, xb.z, xb.y, xb.x)
      xa = na;
      xb = nb;
    }
    RUN8(xa.w, xa.z, xa.y, xa.x, xb.w, xb.z, xb.y, xb.x)
  }

  // Epilogue: h_i = 1 + M2S*r'_i (true scale; no global unscale needed).
  float h0 = __builtin_fmaf(r0v, M2Sc, 1.0f);
  float h1 = __builtin_fmaf(r1v, M2Sc, 1.0f);
  float h2 = __builtin_fmaf(r2v, M2Sc, 1.0f);
  float p = wfc0 * h0;
  p = __builtin_fmaf(wfc1, h1, p);
  p = __builtin_fmaf(wfc2, h2, p);
  p += SWZF(p, 0x041F);  // xor 1
  p += SWZF(p, 0x081F);  // xor 2
  p += SWZF(p, 0x101F);  // xor 4
  p += SWZF(p, 0x201F);  // xor 8 -> sum over the 16-lane chain pair
  if ((lane & 15) == 0) {
    int oidx = d * (BB / 2) + blk * 4 + (g >> 1);
    out[oidx] = p + bfc[0];
  }
}

extern "C" void kernel_launch(void* const* d_in, const int* in_sizes, int n_in,
                              void* d_out, int out_size, void* d_ws,
                              size_t ws_size, hipStream_t stream) {
  (void)in_sizes; (void)n_in; (void)d_ws; (void)ws_size; (void)out_size;
  const float* x     = (const float*)d_in[0];
  const float* Wih_f = (const float*)d_in[1];
  const float* Whh_f = (const float*)d_in[2];
  const float* bih_f = (const float*)d_in[3];
  const float* bhh_f = (const float*)d_in[4];
  const float* Wih_b = (const float*)d_in[5];
  const float* Whh_b = (const float*)d_in[6];
  const float* bih_b = (const float*)d_in[7];
  const float* bhh_b = (const float*)d_in[8];
  const float* Wfc   = (const float*)d_in[9];
  const float* bfc   = (const float*)d_in[10];
  float* out = (float*)d_out;

  // 512 fwd + 512 bwd blocks, 1 wave each (8 chains/wave) = 1 wave/SIMD.
  hipLaunchKernelGGL(rnn_bidir_kernel, dim3(1024), dim3(64), 0, stream,
                     x, Wih_f, Whh_f, bih_f, bhh_f,
                     Wih_b, Whh_b, bih_b, bhh_b, Wfc, bfc, out);
}